// Round 1
// baseline (240.403 us; speedup 1.0000x reference)
//
#include <hip/hip_runtime.h>

#define EMBED 512
#define HEADS 8
#define HDIM 64
#define NBATCH 4
#define SEQ 2048

typedef __attribute__((ext_vector_type(8))) short short8v;  // 8 bf16 (4 VGPRs)
typedef __attribute__((ext_vector_type(4))) float f32x4;
typedef __attribute__((ext_vector_type(4))) int int4v;

static __device__ __forceinline__ short f2bf(float f) {
  union { float f; unsigned u; } v; v.f = f;
  unsigned r = v.u + 0x7FFFu + ((v.u >> 16) & 1u);  // RNE
  return (short)(r >> 16);
}

// XOR swizzle for 128-byte LDS rows (64 bf16): spreads same-column reads of
// rows 0..7 across 8 distinct 16B chunks -> conflict-free ds_read_b128.
static __device__ __forceinline__ int swz(int row, int b) {
  return row * 128 + (b ^ ((row & 7) << 4));
}

// ---------------- mask packing: uint64 bitmask per 64 key positions ----------
__global__ void __launch_bounds__(256) pack_mask_k(const int* __restrict__ mask,
                                                   unsigned long long* __restrict__ mp) {
  long gid = (long)blockIdx.x * 256 + threadIdx.x;
  int bit = mask[gid] != 0;
  unsigned long long b = __ballot(bit);
  if ((threadIdx.x & 63) == 0) mp[gid >> 6] = b;
}

// ---------------- GEMM: C[M,512] = A[M,512] @ W[512,512]^T -------------------
// A_IS_F32: 1 -> A is f32 (convert to bf16 while staging), 0 -> A is bf16.
// OUT_MODE: 0 -> bf16 C[m][n]; 1 -> bf16 transposed C^T as [n>>6][n&63][m] per
//           batch (vt layout [N][H][D][S]); 2 -> f32 C[m][n] + bias[n].
template <int A_IS_F32, int OUT_MODE>
__global__ void __launch_bounds__(256) gemm512_k(const void* __restrict__ A_,
                                                 const float* __restrict__ W,
                                                 void* __restrict__ C_,
                                                 const float* __restrict__ bias) {
  __shared__ short As[128 * 64];
  __shared__ short Bs[128 * 64];
  const int m0 = blockIdx.x * 128;
  const int n0 = blockIdx.y * 128;
  const int t = threadIdx.x;
  const int lane = t & 63;
  const int wid = t >> 6;
  const int wm = wid >> 1, wn = wid & 1;       // 2x2 waves, 64x64 each
  const int lrow = lane & 15, lgrp = lane >> 4;
  const int srow = t >> 1, shalf = t & 1;      // staging: 2 threads per row

  f32x4 acc[4][4];
#pragma unroll
  for (int i = 0; i < 4; ++i)
#pragma unroll
    for (int j = 0; j < 4; ++j) acc[i][j] = (f32x4){0.f, 0.f, 0.f, 0.f};

  for (int kt = 0; kt < EMBED / 64; ++kt) {
    const int k0 = kt * 64;
    if (kt) __syncthreads();
    // stage A tile [128][64] -> bf16 LDS (swizzled)
    if (A_IS_F32) {
      const f32x4* src = (const f32x4*)((const float*)A_ + (long)(m0 + srow) * EMBED + k0 + shalf * 32);
      short tmp[32];
#pragma unroll
      for (int i = 0; i < 8; ++i) {
        f32x4 v = src[i];
#pragma unroll
        for (int j = 0; j < 4; ++j) tmp[i * 4 + j] = f2bf(v[j]);
      }
#pragma unroll
      for (int c = 0; c < 4; ++c)
        *(int4v*)((char*)As + swz(srow, shalf * 64 + c * 16)) = *(const int4v*)&tmp[c * 8];
    } else {
      const int4v* src = (const int4v*)((const short*)A_ + (long)(m0 + srow) * EMBED + k0 + shalf * 32);
#pragma unroll
      for (int c = 0; c < 4; ++c)
        *(int4v*)((char*)As + swz(srow, shalf * 64 + c * 16)) = src[c];
    }
    // stage W tile [128][64] (rows n, cols k) -> bf16 LDS
    {
      const f32x4* src = (const f32x4*)(W + (long)(n0 + srow) * EMBED + k0 + shalf * 32);
      short tmp[32];
#pragma unroll
      for (int i = 0; i < 8; ++i) {
        f32x4 v = src[i];
#pragma unroll
        for (int j = 0; j < 4; ++j) tmp[i * 4 + j] = f2bf(v[j]);
      }
#pragma unroll
      for (int c = 0; c < 4; ++c)
        *(int4v*)((char*)Bs + swz(srow, shalf * 64 + c * 16)) = *(const int4v*)&tmp[c * 8];
    }
    __syncthreads();
#pragma unroll
    for (int kk = 0; kk < 2; ++kk) {
      short8v af[4], bfr[4];
#pragma unroll
      for (int mi = 0; mi < 4; ++mi)
        af[mi] = *(const short8v*)((const char*)As + swz(wm * 64 + mi * 16 + lrow, kk * 64 + lgrp * 16));
#pragma unroll
      for (int ni = 0; ni < 4; ++ni)
        bfr[ni] = *(const short8v*)((const char*)Bs + swz(wn * 64 + ni * 16 + lrow, kk * 64 + lgrp * 16));
#pragma unroll
      for (int mi = 0; mi < 4; ++mi)
#pragma unroll
        for (int ni = 0; ni < 4; ++ni)
          acc[mi][ni] = __builtin_amdgcn_mfma_f32_16x16x32_bf16(af[mi], bfr[ni], acc[mi][ni], 0, 0, 0);
    }
  }

  // epilogue: C layout col = lane&15, row = (lane>>4)*4 + reg  [m89-verified]
  if (OUT_MODE == 0) {
    short* C = (short*)C_;
#pragma unroll
    for (int mi = 0; mi < 4; ++mi)
#pragma unroll
      for (int ni = 0; ni < 4; ++ni) {
        int m = m0 + wm * 64 + mi * 16 + lgrp * 4;
        int n = n0 + wn * 64 + ni * 16 + lrow;
#pragma unroll
        for (int r = 0; r < 4; ++r)
          C[(long)(m + r) * EMBED + n] = f2bf(acc[mi][ni][r]);
      }
  } else if (OUT_MODE == 1) {
    short* C = (short*)C_;  // vt[N][H][D][S]; 4 consecutive s per lane -> 8B store
#pragma unroll
    for (int mi = 0; mi < 4; ++mi)
#pragma unroll
      for (int ni = 0; ni < 4; ++ni) {
        int m = m0 + wm * 64 + mi * 16 + lgrp * 4;
        int ncol = n0 + wn * 64 + ni * 16 + lrow;
        int batch = m >> 11, s = m & (SEQ - 1);
        int h = ncol >> 6, d = ncol & (HDIM - 1);
        short pk[4];
#pragma unroll
        for (int r = 0; r < 4; ++r) pk[r] = f2bf(acc[mi][ni][r]);
        *(unsigned long long*)&C[((long)((batch * HEADS + h) * HDIM + d)) * SEQ + s] =
            *(const unsigned long long*)pk;
      }
  } else {
    float* C = (float*)C_;
#pragma unroll
    for (int mi = 0; mi < 4; ++mi)
#pragma unroll
      for (int ni = 0; ni < 4; ++ni) {
        int m = m0 + wm * 64 + mi * 16 + lgrp * 4;
        int n = n0 + wn * 64 + ni * 16 + lrow;
        float b = bias[n];
#pragma unroll
        for (int r = 0; r < 4; ++r)
          C[(long)(m + r) * EMBED + n] = acc[mi][ni][r] + b;
      }
  }
}

// ---------------- flash attention: per (n, h, 64-row q tile) -----------------
// Q raw (bug-faithful: q_proj discarded). logits = (q.k)/sqrt(512); mask==0 -> -inf.
__global__ void __launch_bounds__(256) attn_k(const float* __restrict__ query,
                                              const short* __restrict__ kbf,
                                              const short* __restrict__ vt,
                                              const unsigned long long* __restrict__ mp,
                                              short* __restrict__ oat) {
  __shared__ short Qs[64 * 64];
  __shared__ short Ks[64 * 64];
  __shared__ short Vs[64 * 64];   // V^T tile: rows = d, cols = kpos
  __shared__ short Ps[4][16 * 64];  // wave-private P tiles
  const int qt = blockIdx.x, h = blockIdx.y, nb = blockIdx.z;
  const int q0 = qt * 64;
  const int t = threadIdx.x, lane = t & 63, wid = t >> 6;
  const int lrow = lane & 15, lgrp = lane >> 4;
  const float KS = 0.0637587188f;  // log2(e)/sqrt(512)

  // stage Q tile [64 q][64 d] f32 -> bf16 (swizzled)
  {
    int row = t >> 2, c4 = t & 3;
    const f32x4* src = (const f32x4*)(query + (long)(nb * SEQ + q0 + row) * EMBED + h * HDIM) + c4 * 4;
    short tmp[16];
#pragma unroll
    for (int i = 0; i < 4; ++i) {
      f32x4 v = src[i];
#pragma unroll
      for (int j = 0; j < 4; ++j) tmp[i * 4 + j] = f2bf(v[j]);
    }
#pragma unroll
    for (int c = 0; c < 2; ++c)
      *(int4v*)((char*)Qs + swz(row, c4 * 32 + c * 16)) = *(const int4v*)&tmp[c * 8];
  }
  __syncthreads();
  short8v qf[2];  // wave's 16 q-rows, kept in registers for the whole k-loop
  qf[0] = *(const short8v*)((const char*)Qs + swz(wid * 16 + lrow, lgrp * 16));
  qf[1] = *(const short8v*)((const char*)Qs + swz(wid * 16 + lrow, 64 + lgrp * 16));

  float mr[4] = {-1e30f, -1e30f, -1e30f, -1e30f};
  float lr[4] = {0.f, 0.f, 0.f, 0.f};
  f32x4 oacc[4];
#pragma unroll
  for (int nf = 0; nf < 4; ++nf) oacc[nf] = (f32x4){0.f, 0.f, 0.f, 0.f};

  for (int kt = 0; kt < SEQ / 64; ++kt) {
    const int k0 = kt * 64;
    {  // stage K [64 kpos][64 d] and V^T [64 d][64 kpos]
      int row = t >> 2, cc = t & 3;
      const int4v* ks = (const int4v*)(kbf + (long)(nb * SEQ + k0 + row) * EMBED + h * HDIM);
      const int4v* vs = (const int4v*)(vt + ((long)(nb * HEADS + h) * HDIM + row) * SEQ + k0);
#pragma unroll
      for (int i = 0; i < 2; ++i) {
        *(int4v*)((char*)Ks + swz(row, (cc * 2 + i) * 16)) = ks[cc * 2 + i];
        *(int4v*)((char*)Vs + swz(row, (cc * 2 + i) * 16)) = vs[cc * 2 + i];
      }
    }
    __syncthreads();

    // S = Q.K^T : 4 col-fragments of 16 kpos each
    f32x4 sf[4];
#pragma unroll
    for (int nf = 0; nf < 4; ++nf) {
      short8v kf0 = *(const short8v*)((const char*)Ks + swz(nf * 16 + lrow, lgrp * 16));
      short8v kf1 = *(const short8v*)((const char*)Ks + swz(nf * 16 + lrow, 64 + lgrp * 16));
      f32x4 z = (f32x4){0.f, 0.f, 0.f, 0.f};
      z = __builtin_amdgcn_mfma_f32_16x16x32_bf16(qf[0], kf0, z, 0, 0, 0);
      sf[nf] = __builtin_amdgcn_mfma_f32_16x16x32_bf16(qf[1], kf1, z, 0, 0, 0);
    }

    // online softmax, rows q = wid*16 + lgrp*4 + r, cols k = k0 + nf*16 + lrow
    float al[4];
#pragma unroll
    for (int r = 0; r < 4; ++r) {
      unsigned long long mw = mp[(long)(nb * SEQ + q0 + wid * 16 + lgrp * 4 + r) * (SEQ / 64) + kt];
      float sv[4];
      float tm = -1e30f;
#pragma unroll
      for (int nf = 0; nf < 4; ++nf) {
        float x = sf[nf][r];
        x = ((mw >> (nf * 16 + lrow)) & 1ull) ? x : -1e30f;
        sv[nf] = x;
        tm = fmaxf(tm, x);
      }
      tm = fmaxf(tm, __shfl_xor(tm, 1));
      tm = fmaxf(tm, __shfl_xor(tm, 2));
      tm = fmaxf(tm, __shfl_xor(tm, 4));
      tm = fmaxf(tm, __shfl_xor(tm, 8));
      float mn = fmaxf(mr[r], tm);
      al[r] = exp2f((mr[r] - mn) * KS);
      mr[r] = mn;
      float ps = 0.f;
#pragma unroll
      for (int nf = 0; nf < 4; ++nf) {
        float p = exp2f((sv[nf] - mn) * KS);
        ps += p;
        // transpose C-layout -> A-layout via wave-private LDS
        *((short*)((char*)Ps[wid] + swz(lgrp * 4 + r, (nf * 16 + lrow) * 2))) = f2bf(p);
      }
      ps += __shfl_xor(ps, 1);
      ps += __shfl_xor(ps, 2);
      ps += __shfl_xor(ps, 4);
      ps += __shfl_xor(ps, 8);
      lr[r] = lr[r] * al[r] + ps;
    }
#pragma unroll
    for (int nf = 0; nf < 4; ++nf) {
      f32x4 o = oacc[nf];
      o[0] *= al[0]; o[1] *= al[1]; o[2] *= al[2]; o[3] *= al[3];
      oacc[nf] = o;
    }

    // O += P.V  (A-frags from Ps, B-frags from V^T tile)
    short8v pf0 = *(const short8v*)((const char*)Ps[wid] + swz(lrow, lgrp * 16));
    short8v pf1 = *(const short8v*)((const char*)Ps[wid] + swz(lrow, 64 + lgrp * 16));
#pragma unroll
    for (int nf = 0; nf < 4; ++nf) {
      short8v vf0 = *(const short8v*)((const char*)Vs + swz(nf * 16 + lrow, lgrp * 16));
      short8v vf1 = *(const short8v*)((const char*)Vs + swz(nf * 16 + lrow, 64 + lgrp * 16));
      oacc[nf] = __builtin_amdgcn_mfma_f32_16x16x32_bf16(pf0, vf0, oacc[nf], 0, 0, 0);
      oacc[nf] = __builtin_amdgcn_mfma_f32_16x16x32_bf16(pf1, vf1, oacc[nf], 0, 0, 0);
    }
    __syncthreads();
  }

  // epilogue: out_attn[n][q][h*64+d] bf16
#pragma unroll
  for (int nf = 0; nf < 4; ++nf) {
#pragma unroll
    for (int r = 0; r < 4; ++r) {
      int q = q0 + wid * 16 + lgrp * 4 + r;
      int e = h * HDIM + nf * 16 + lrow;
      oat[(long)(nb * SEQ + q) * EMBED + e] = f2bf(oacc[nf][r] / lr[r]);
    }
  }
}

extern "C" void kernel_launch(void* const* d_in, const int* in_sizes, int n_in,
                              void* d_out, int out_size, void* d_ws, size_t ws_size,
                              hipStream_t stream) {
  const float* values = (const float*)d_in[0];
  const float* keys   = (const float*)d_in[1];
  const float* query  = (const float*)d_in[2];
  const int*   mask   = (const int*)d_in[3];
  // d_in[4] = Wq: computed-then-discarded in the reference (bug-faithful skip)
  const float* Wk = (const float*)d_in[5];
  const float* Wv = (const float*)d_in[6];
  const float* Wo = (const float*)d_in[7];
  const float* bo = (const float*)d_in[8];
  float* out = (float*)d_out;

  // workspace layout (26 MB total)
  char* ws = (char*)d_ws;
  short* kbf = (short*)ws;                                        // 8 MB  [N][S][E] bf16
  short* vt  = (short*)(ws + (8u << 20));                         // 8 MB  [N][H][D][S] bf16
  short* oat = (short*)(ws + (16u << 20));                        // 8 MB  [N][S][E] bf16
  unsigned long long* mp = (unsigned long long*)(ws + (24u << 20)); // 2 MB packed mask

  pack_mask_k<<<(NBATCH * SEQ * SEQ) / 256, 256, 0, stream>>>(mask, mp);
  gemm512_k<1, 0><<<dim3((NBATCH * SEQ) / 128, EMBED / 128), 256, 0, stream>>>(keys, Wk, kbf, nullptr);
  gemm512_k<1, 1><<<dim3((NBATCH * SEQ) / 128, EMBED / 128), 256, 0, stream>>>(values, Wv, vt, nullptr);
  attn_k<<<dim3(SEQ / 64, HEADS, NBATCH), 256, 0, stream>>>(query, kbf, vt, mp, oat);
  gemm512_k<0, 2><<<dim3((NBATCH * SEQ) / 128, EMBED / 128), 256, 0, stream>>>(oat, Wo, out, bo);
}

// Round 2
// 163.704 us; speedup vs baseline: 1.4685x; 1.4685x over previous
//
#include <hip/hip_runtime.h>

#define EMBED 512
#define HEADS 8
#define HDIM 64
#define NBATCH 4
#define SEQ 2048
#define KVB 64
#define NT (SEQ / KVB)  // 32

typedef __attribute__((ext_vector_type(8))) short short8v;   // 8 bf16
typedef __attribute__((ext_vector_type(4))) float f32x4;
typedef __attribute__((ext_vector_type(16))) float f32x16;
typedef __attribute__((ext_vector_type(4))) int int4v;

#if __has_builtin(__builtin_amdgcn_exp2f)
#define EXP2(x) __builtin_amdgcn_exp2f(x)
#else
#define EXP2(x) exp2f(x)
#endif

static __device__ __forceinline__ short f2bf(float f) {
  union { float f; unsigned u; } v; v.f = f;
  unsigned r = v.u + 0x7FFFu + ((v.u >> 16) & 1u);  // RNE
  return (short)(r >> 16);
}

static __device__ __forceinline__ int cvtpk(float a, float b) {
  int r;
  asm("v_cvt_pk_bf16_f32 %0, %1, %2" : "=v"(r) : "v"(a), "v"(b));
  return r;  // low half = bf16(a), high half = bf16(b)
}

// XOR swizzle for 128-byte LDS rows: conflict-free ds_read_b128 column reads.
static __device__ __forceinline__ int swz(int row, int b) {
  return row * 128 + (b ^ ((row & 7) << 4));
}

// ---------------- mask packing: word per (n, kt, q) -- [n][kt][q] layout -----
__global__ void __launch_bounds__(256) pack_mask_k(const int* __restrict__ mask,
                                                   unsigned long long* __restrict__ mp) {
  long gid = (long)blockIdx.x * 256 + threadIdx.x;
  int bit = mask[gid] != 0;
  unsigned long long b = __ballot(bit);
  if ((threadIdx.x & 63) == 0) {
    long w = gid >> 6;             // (n*SEQ + q)*NT + kt
    int kt = (int)(w & (NT - 1));
    long nq = w >> 5;              // n*SEQ + q
    int q = (int)(nq & (SEQ - 1));
    int n = (int)(nq >> 11);
    mp[((long)(n * NT + kt) << 11) + q] = b;
  }
}

// ---------------- GEMM: C[M,512] = A[M,512] @ W[512,512]^T (unchanged) -------
template <int A_IS_F32, int OUT_MODE>
__global__ void __launch_bounds__(256) gemm512_k(const void* __restrict__ A_,
                                                 const float* __restrict__ W,
                                                 void* __restrict__ C_,
                                                 const float* __restrict__ bias) {
  __shared__ short As[128 * 64];
  __shared__ short Bs[128 * 64];
  const int m0 = blockIdx.x * 128;
  const int n0 = blockIdx.y * 128;
  const int t = threadIdx.x;
  const int lane = t & 63;
  const int wid = t >> 6;
  const int wm = wid >> 1, wn = wid & 1;
  const int lrow = lane & 15, lgrp = lane >> 4;
  const int srow = t >> 1, shalf = t & 1;

  f32x4 acc[4][4];
#pragma unroll
  for (int i = 0; i < 4; ++i)
#pragma unroll
    for (int j = 0; j < 4; ++j) acc[i][j] = (f32x4){0.f, 0.f, 0.f, 0.f};

  for (int kt = 0; kt < EMBED / 64; ++kt) {
    const int k0 = kt * 64;
    if (kt) __syncthreads();
    if (A_IS_F32) {
      const f32x4* src = (const f32x4*)((const float*)A_ + (long)(m0 + srow) * EMBED + k0 + shalf * 32);
      short tmp[32];
#pragma unroll
      for (int i = 0; i < 8; ++i) {
        f32x4 v = src[i];
#pragma unroll
        for (int j = 0; j < 4; ++j) tmp[i * 4 + j] = f2bf(v[j]);
      }
#pragma unroll
      for (int c = 0; c < 4; ++c)
        *(int4v*)((char*)As + swz(srow, shalf * 64 + c * 16)) = *(const int4v*)&tmp[c * 8];
    } else {
      const int4v* src = (const int4v*)((const short*)A_ + (long)(m0 + srow) * EMBED + k0 + shalf * 32);
#pragma unroll
      for (int c = 0; c < 4; ++c)
        *(int4v*)((char*)As + swz(srow, shalf * 64 + c * 16)) = src[c];
    }
    {
      const f32x4* src = (const f32x4*)(W + (long)(n0 + srow) * EMBED + k0 + shalf * 32);
      short tmp[32];
#pragma unroll
      for (int i = 0; i < 8; ++i) {
        f32x4 v = src[i];
#pragma unroll
        for (int j = 0; j < 4; ++j) tmp[i * 4 + j] = f2bf(v[j]);
      }
#pragma unroll
      for (int c = 0; c < 4; ++c)
        *(int4v*)((char*)Bs + swz(srow, shalf * 64 + c * 16)) = *(const int4v*)&tmp[c * 8];
    }
    __syncthreads();
#pragma unroll
    for (int kk = 0; kk < 2; ++kk) {
      short8v af[4], bfr[4];
#pragma unroll
      for (int mi = 0; mi < 4; ++mi)
        af[mi] = *(const short8v*)((const char*)As + swz(wm * 64 + mi * 16 + lrow, kk * 64 + lgrp * 16));
#pragma unroll
      for (int ni = 0; ni < 4; ++ni)
        bfr[ni] = *(const short8v*)((const char*)Bs + swz(wn * 64 + ni * 16 + lrow, kk * 64 + lgrp * 16));
#pragma unroll
      for (int mi = 0; mi < 4; ++mi)
#pragma unroll
        for (int ni = 0; ni < 4; ++ni)
          acc[mi][ni] = __builtin_amdgcn_mfma_f32_16x16x32_bf16(af[mi], bfr[ni], acc[mi][ni], 0, 0, 0);
    }
  }

  if (OUT_MODE == 0) {
    short* C = (short*)C_;
#pragma unroll
    for (int mi = 0; mi < 4; ++mi)
#pragma unroll
      for (int ni = 0; ni < 4; ++ni) {
        int m = m0 + wm * 64 + mi * 16 + lgrp * 4;
        int n = n0 + wn * 64 + ni * 16 + lrow;
#pragma unroll
        for (int r = 0; r < 4; ++r)
          C[(long)(m + r) * EMBED + n] = f2bf(acc[mi][ni][r]);
      }
  } else if (OUT_MODE == 1) {
    short* C = (short*)C_;  // vt[N][H][D][S]
#pragma unroll
    for (int mi = 0; mi < 4; ++mi)
#pragma unroll
      for (int ni = 0; ni < 4; ++ni) {
        int m = m0 + wm * 64 + mi * 16 + lgrp * 4;
        int ncol = n0 + wn * 64 + ni * 16 + lrow;
        int batch = m >> 11, s = m & (SEQ - 1);
        int h = ncol >> 6, d = ncol & (HDIM - 1);
        short pk[4];
#pragma unroll
        for (int r = 0; r < 4; ++r) pk[r] = f2bf(acc[mi][ni][r]);
        *(unsigned long long*)&C[((long)((batch * HEADS + h) * HDIM + d)) * SEQ + s] =
            *(const unsigned long long*)pk;
      }
  } else {
    float* C = (float*)C_;
#pragma unroll
    for (int mi = 0; mi < 4; ++mi)
#pragma unroll
      for (int ni = 0; ni < 4; ++ni) {
        int m = m0 + wm * 64 + mi * 16 + lgrp * 4;
        int n = n0 + wn * 64 + ni * 16 + lrow;
        float b = bias[n];
#pragma unroll
        for (int r = 0; r < 4; ++r)
          C[(long)(m + r) * EMBED + n] = acc[mi][ni][r] + b;
      }
  }
}

// ---------------- flash attention v2: 32x32 swapped-QK^T, in-reg softmax -----
// Wave = 32 q rows. Block = 4 waves = 128 q rows. Grid = 512 blocks.
// S^T = K.Q^T via mfma_32x32x16 (A=K, B=Q^T): lane holds P rows lane-locally.
__global__ void __launch_bounds__(256, 2) attn_k(const float* __restrict__ query,
                                                 const short* __restrict__ kbf,
                                                 const short* __restrict__ vt,
                                                 const unsigned long long* __restrict__ mpt,
                                                 short* __restrict__ oat) {
  __shared__ short Qs[128 * 64];        // 16 KB
  __shared__ short Kbuf[2][KVB * 64];   // 16 KB (double-buffered)
  __shared__ short Vbuf[2][KVB * 64];   // 16 KB

  // XCD-chunked swizzle: the 16 q-tiles of one (n,h) land on one XCD's L2.
  const int bid = blockIdx.x;
  const int logical = ((bid & 7) << 6) | (bid >> 3);  // 512 = 8 * 64, bijective
  const int qt = logical & 15;
  const int h = (logical >> 4) & 7;
  const int nb = logical >> 7;
  const int q0 = qt * 128;
  const int t = threadIdx.x, lane = t & 63, wid = t >> 6;
  const int ql = lane & 31, hi = lane >> 5;
  const float KS = 0.0637587188f;  // log2(e)/sqrt(512)

  // ---- stage Q [128 q][64 d] f32 -> bf16 (swizzled), once ----
  {
    int row = t >> 1, half = t & 1;
    const f32x4* src = (const f32x4*)(query + (long)(nb * SEQ + q0 + row) * EMBED + h * HDIM + half * 32);
    short tmp[32];
#pragma unroll
    for (int i = 0; i < 8; ++i) {
      f32x4 v = src[i];
#pragma unroll
      for (int j = 0; j < 4; ++j) tmp[i * 4 + j] = f2bf(v[j]);
    }
#pragma unroll
    for (int c = 0; c < 4; ++c)
      *(int4v*)((char*)Qs + swz(row, half * 64 + c * 16)) = *(const int4v*)&tmp[c * 8];
  }

  // ---- K/V staging: thread -> (row = t>>2, 32B chunk = t&3), coalesced ----
  const int srow = t >> 2, sc = t & 3;
  const short* kg0 = kbf + (long)(nb * SEQ + srow) * EMBED + h * HDIM + sc * 16;
  const short* vg0 = vt + ((long)((nb * HEADS + h) * HDIM) + srow) * SEQ + sc * 16;
  int4v kr0, kr1, vr0, vr1;
#define LOADT(k0_)                                         \
  {                                                        \
    const int4v* kp = (const int4v*)(kg0 + (long)(k0_) * EMBED); \
    kr0 = kp[0]; kr1 = kp[1];                              \
    const int4v* vp = (const int4v*)(vg0 + (k0_));         \
    vr0 = vp[0]; vr1 = vp[1];                              \
  }
#define WRT(b_)                                                          \
  {                                                                      \
    *(int4v*)((char*)Kbuf[b_] + swz(srow, (sc * 2 + 0) * 16)) = kr0;     \
    *(int4v*)((char*)Kbuf[b_] + swz(srow, (sc * 2 + 1) * 16)) = kr1;     \
    *(int4v*)((char*)Vbuf[b_] + swz(srow, (sc * 2 + 0) * 16)) = vr0;     \
    *(int4v*)((char*)Vbuf[b_] + swz(srow, (sc * 2 + 1) * 16)) = vr1;     \
  }
  LOADT(0);
  WRT(0);
  __syncthreads();

  // ---- Q^T B-fragments, kept in registers for the whole loop ----
  short8v qf[4];
#pragma unroll
  for (int ks = 0; ks < 4; ++ks)
    qf[ks] = *(const short8v*)((const char*)Qs + swz(wid * 32 + ql, ks * 32 + hi * 16));

  f32x16 ot0, ot1;
#pragma unroll
  for (int i = 0; i < 16; ++i) { ot0[i] = 0.f; ot1[i] = 0.f; }
  float mr = -3.0e38f, lr = 0.f;

  const unsigned long long* mrow = mpt + ((long)nb * NT << 11) + (q0 + wid * 32 + ql);
  unsigned long long mw = mrow[0];

  for (int tt = 0; tt < NT; ++tt) {
    const int cur = tt & 1;
    if (tt < NT - 1) LOADT((tt + 1) * KVB);               // issue-early (T14)
    unsigned long long mw_next = (tt < NT - 1) ? mrow[(long)(tt + 1) << 11] : 0ull;

    // ---- S^T = K.Q^T : 2 kpos-tiles x 4 d-slices ----
    f32x16 st0, st1;
#pragma unroll
    for (int i = 0; i < 16; ++i) { st0[i] = 0.f; st1[i] = 0.f; }
    const char* kb = (const char*)Kbuf[cur];
#pragma unroll
    for (int ks = 0; ks < 4; ++ks) {
      short8v ka = *(const short8v*)(kb + swz(ql, ks * 32 + hi * 16));
      short8v kc = *(const short8v*)(kb + swz(32 + ql, ks * 32 + hi * 16));
      st0 = __builtin_amdgcn_mfma_f32_32x32x16_bf16(ka, qf[ks], st0, 0, 0, 0);
      st1 = __builtin_amdgcn_mfma_f32_32x32x16_bf16(kc, qf[ks], st1, 0, 0, 0);
    }

    // ---- row max over raw S (masking not needed for a valid max) ----
    float a0 = st0[0], a1 = st0[1], a2 = st0[2], a3 = st0[3];
#pragma unroll
    for (int r = 4; r < 16; r += 4) {
      a0 = fmaxf(a0, st0[r]); a1 = fmaxf(a1, st0[r + 1]);
      a2 = fmaxf(a2, st0[r + 2]); a3 = fmaxf(a3, st0[r + 3]);
    }
#pragma unroll
    for (int r = 0; r < 16; r += 4) {
      a0 = fmaxf(a0, st1[r]); a1 = fmaxf(a1, st1[r + 1]);
      a2 = fmaxf(a2, st1[r + 2]); a3 = fmaxf(a3, st1[r + 3]);
    }
    float tm = fmaxf(fmaxf(a0, a1), fmaxf(a2, a3));
    tm = fmaxf(tm, __shfl_xor(tm, 32));
    float mn = fmaxf(mr, tm);
    if (!__all(mn - mr <= 60.0f)) {                       // defer-max (T13)
      float al = EXP2((mr - mn) * KS);
#pragma unroll
      for (int i = 0; i < 16; ++i) { ot0[i] *= al; ot1[i] *= al; }
      lr *= al;
      mr = mn;
    }

    // ---- p = exp2(s*KS - mr*KS), masked -> 0 ----
    unsigned long long mws = mw >> (hi << 2);
    unsigned mlo = (unsigned)mws, mhi2 = (unsigned)(mws >> 32);
    const float mk = mr * KS;
#pragma unroll
    for (int r = 0; r < 16; ++r) {
      const int c = (r & 3) + 8 * (r >> 2);
      float p0 = EXP2(st0[r] * KS - mk);
      float p1 = EXP2(st1[r] * KS - mk);
      st0[r] = ((mlo >> c) & 1u) ? p0 : 0.f;
      st1[r] = ((mhi2 >> c) & 1u) ? p1 : 0.f;
    }

    // ---- row sum ----
    float s0 = st0[0], s1 = st0[1], s2 = st0[2], s3 = st0[3];
#pragma unroll
    for (int r = 4; r < 16; r += 4) {
      s0 += st0[r]; s1 += st0[r + 1]; s2 += st0[r + 2]; s3 += st0[r + 3];
    }
#pragma unroll
    for (int r = 0; r < 16; r += 4) {
      s0 += st1[r]; s1 += st1[r + 1]; s2 += st1[r + 2]; s3 += st1[r + 3];
    }
    float ps = (s0 + s1) + (s2 + s3);
    ps += __shfl_xor(ps, 32);
    lr += ps;

    // ---- pack P -> bf16 B-frags + O^T += V^T.P^T ----
    float pp[32];
#pragma unroll
    for (int r = 0; r < 16; ++r) { pp[r] = st0[r]; pp[16 + r] = st1[r]; }
    const char* vb = (const char*)Vbuf[cur];
#pragma unroll
    for (int ks = 0; ks < 4; ++ks) {
      int d0 = cvtpk(pp[8 * ks + 0], pp[8 * ks + 1]);
      int d1 = cvtpk(pp[8 * ks + 2], pp[8 * ks + 3]);
      int d2 = cvtpk(pp[8 * ks + 4], pp[8 * ks + 5]);
      int d3 = cvtpk(pp[8 * ks + 6], pp[8 * ks + 7]);
      int sa = __shfl_xor(d0, 32), sb = __shfl_xor(d2, 32);
      int sc2 = __shfl_xor(d1, 32), sd = __shfl_xor(d3, 32);
      int w0 = hi ? sb : d0;   // cross-half redistribution (derivation in notes)
      int w2 = hi ? d2 : sa;
      int w1 = hi ? sd : d1;
      int w3 = hi ? d3 : sc2;
      union { int4v i; short8v s; } u;
      u.i = (int4v){w0, w1, w2, w3};
      short8v va = *(const short8v*)(vb + swz(ql, ks * 32 + hi * 16));
      short8v vc = *(const short8v*)(vb + swz(32 + ql, ks * 32 + hi * 16));
      ot0 = __builtin_amdgcn_mfma_f32_32x32x16_bf16(va, u.s, ot0, 0, 0, 0);
      ot1 = __builtin_amdgcn_mfma_f32_32x32x16_bf16(vc, u.s, ot1, 0, 0, 0);
    }

    mw = mw_next;
    __syncthreads();                                      // done reading buf[cur]
    if (tt < NT - 1) WRT(cur ^ 1);                        // write-late (T14)
    __syncthreads();
  }

  // ---- epilogue: per-wave LDS transpose -> coalesced 16B stores ----
  float linv = 1.0f / lr;
  float oo[32];
#pragma unroll
  for (int i = 0; i < 16; ++i) { oo[i] = ot0[i] * linv; oo[16 + i] = ot1[i] * linv; }
  short* osl = (short*)Kbuf + wid * 2048;  // wave-private 4KB: [32 q][64 d] swizzled
#pragma unroll
  for (int a = 0; a < 2; ++a)
#pragma unroll
    for (int r = 0; r < 16; r += 2) {
      int db = (r & 3) + 8 * (r >> 2) + 4 * hi + 32 * a;
      int w = cvtpk(oo[a * 16 + r], oo[a * 16 + r + 1]);
      *(int*)((char*)osl + ql * 128 + ((2 * db) ^ ((ql & 7) << 4))) = w;
    }
  int rrow = lane >> 1;
#pragma unroll
  for (int i = 0; i < 4; ++i) {
    int ci = (lane & 1) * 4 + i;
    int4v v = *(const int4v*)((const char*)osl - (long)(lane >> 31) /*keep base*/ + rrow * 128 + ((ci * 16) ^ ((rrow & 7) << 4)));
    *(int4v*)(oat + (long)(nb * SEQ + q0 + wid * 32 + rrow) * EMBED + h * HDIM + ci * 8) = v;
  }
#undef LOADT
#undef WRT
}

extern "C" void kernel_launch(void* const* d_in, const int* in_sizes, int n_in,
                              void* d_out, int out_size, void* d_ws, size_t ws_size,
                              hipStream_t stream) {
  const float* values = (const float*)d_in[0];
  const float* keys   = (const float*)d_in[1];
  const float* query  = (const float*)d_in[2];
  const int*   mask   = (const int*)d_in[3];
  // d_in[4] = Wq: computed-then-discarded in the reference (bug-faithful skip)
  const float* Wk = (const float*)d_in[5];
  const float* Wv = (const float*)d_in[6];
  const float* Wo = (const float*)d_in[7];
  const float* bo = (const float*)d_in[8];
  float* out = (float*)d_out;

  char* ws = (char*)d_ws;
  short* kbf = (short*)ws;                                          // 8 MB [N][S][E] bf16
  short* vtw = (short*)(ws + (8u << 20));                           // 8 MB [N][H][D][S] bf16
  short* oat = (short*)(ws + (16u << 20));                          // 8 MB [N][S][E] bf16
  unsigned long long* mpt = (unsigned long long*)(ws + (24u << 20)); // 2 MB [N][NT][S]

  pack_mask_k<<<(NBATCH * SEQ * SEQ) / 256, 256, 0, stream>>>(mask, mpt);
  gemm512_k<1, 0><<<dim3((NBATCH * SEQ) / 128, EMBED / 128), 256, 0, stream>>>(keys, Wk, kbf, nullptr);
  gemm512_k<1, 1><<<dim3((NBATCH * SEQ) / 128, EMBED / 128), 256, 0, stream>>>(values, Wv, vtw, nullptr);
  attn_k<<<dim3(16 * HEADS * NBATCH), 256, 0, stream>>>(query, kbf, vtw, mpt, oat);
  gemm512_k<0, 2><<<dim3((NBATCH * SEQ) / 128, EMBED / 128), 256, 0, stream>>>(oat, Wo, out, bo);
}